// Round 2
// baseline (115.613 us; speedup 1.0000x reference)
//
#include <hip/hip_runtime.h>
#include <hip/hip_cooperative_groups.h>

namespace cg = cooperative_groups;

// Problem constants (from reference): T=26246, B=128, IN=6, H=1.
#define T_LEN 26246
#define B_SZ  128
#define IN_SZ 6
// 2*log2(e): tanh(z) = 1 - 2/(2^(SCALE*z) + 1)
#define SCALE 2.88539008177792681472f

// Cooperative fused config
#define NBLK  256
#define NTHR  256
#define CHUNK 112   // output steps per chunk
#define WARM  112   // warm-up steps: |w|^112 << absmax threshold
#define UNR   16    // prefetch depth (double-buffered)
#define NCH   ((T_LEN + CHUNK - 1) / CHUNK)   // 235 chunks (<= NBLK)

// ================= Cooperative single kernel: projection + grid.sync + scan ==============
__global__ __launch_bounds__(NTHR) void rnn_fused(
    const float* __restrict__ x, const float* __restrict__ W_ih,
    const float* __restrict__ W_hh, const float* __restrict__ b_ih,
    const float* __restrict__ b_hh, const float* __restrict__ fc_w,
    const float* __restrict__ fc_b, float* __restrict__ A,
    float* __restrict__ out) {
  // ---- Phase 1: A[t,b] = SCALE*(x[t,b,:]·W_ih + b_ih + b_hh), grid-stride,
  //      each iteration handles TWO (t,b) elements = 12 floats (3x float4). ----
  {
    const float w0 = W_ih[0], w1 = W_ih[1], w2 = W_ih[2],
                w3 = W_ih[3], w4 = W_ih[4], w5 = W_ih[5];
    const float bias = b_ih[0] + b_hh[0];
    const int n2 = (T_LEN * B_SZ) / 2;
    for (int i = blockIdx.x * NTHR + threadIdx.x; i < n2; i += NBLK * NTHR) {
      const float4* xp = (const float4*)(x + (size_t)i * 12);
      float4 a = xp[0], b = xp[1], c = xp[2];
      float d0 = a.x*w0 + a.y*w1 + a.z*w2 + a.w*w3 + b.x*w4 + b.y*w5 + bias;
      float d1 = b.z*w0 + b.w*w1 + c.x*w2 + c.y*w3 + c.z*w4 + c.w*w5 + bias;
      float2 r; r.x = SCALE * d0; r.y = SCALE * d1;
      ((float2*)A)[i] = r;
    }
  }
  __threadfence();           // device-scope release: make A visible across XCD L2s
  cg::this_grid().sync();
  __threadfence();           // device-scope acquire: invalidate stale cached A

  // ---- Phase 2: chunked scan with warm-up; block = chunk, lane = batch elem ----
  if (blockIdx.x >= NCH || threadIdx.x >= B_SZ) return;
  const int b  = threadIdx.x;
  const int c  = blockIdx.x;
  const int t0 = c * CHUNK;
  const int tw = (c == 0) ? 0 : (t0 - WARM);
  const float w2 = SCALE * W_hh[0];
  const float fw = fc_w[0], fb = fc_b[0];

  float h = 0.0f;
  float buf[UNR], nbuf[UNR];
  #pragma unroll
  for (int j = 0; j < UNR; ++j) {
    int t = tw + j; t = (t < T_LEN) ? t : (T_LEN - 1);
    buf[j] = A[t * B_SZ + b];
  }
  const int tlim = t0 + CHUNK;  // (tlim - tw) is a multiple of UNR (112 or 224)
  for (int tb = tw; tb < tlim; tb += UNR) {
    #pragma unroll
    for (int j = 0; j < UNR; ++j) {
      int t = tb + UNR + j; t = (t < T_LEN) ? t : (T_LEN - 1);
      nbuf[j] = A[t * B_SZ + b];
    }
    #pragma unroll
    for (int j = 0; j < UNR; ++j) {
      const int t = tb + j;
      float g = fmaf(h, w2, buf[j]);
      float u = __builtin_amdgcn_exp2f(g);
      float r = __builtin_amdgcn_rcpf(u + 1.0f);
      h = fmaf(-2.0f, r, 1.0f);
      if (t >= t0 && t < T_LEN) out[t * B_SZ + b] = fmaf(h, fw, fb);
    }
    #pragma unroll
    for (int j = 0; j < UNR; ++j) buf[j] = nbuf[j];
  }
}

// ================= Fallback path (proven in R1): two kernels =================
__global__ __launch_bounds__(256) void inproj_kernel(
    const float* __restrict__ x, const float* __restrict__ W_ih,
    const float* __restrict__ b_ih, const float* __restrict__ b_hh,
    float* __restrict__ A, int n2) {
  int i = blockIdx.x * 256 + threadIdx.x;
  if (i >= n2) return;
  const float w0 = W_ih[0], w1 = W_ih[1], w2 = W_ih[2],
              w3 = W_ih[3], w4 = W_ih[4], w5 = W_ih[5];
  const float bias = b_ih[0] + b_hh[0];
  const float4* xp = (const float4*)(x + (size_t)i * 12);
  float4 a = xp[0], b = xp[1], c = xp[2];
  float d0 = a.x*w0 + a.y*w1 + a.z*w2 + a.w*w3 + b.x*w4 + b.y*w5 + bias;
  float d1 = b.z*w0 + b.w*w1 + c.x*w2 + c.y*w3 + c.z*w4 + c.w*w5 + bias;
  float2 r; r.x = SCALE * d0; r.y = SCALE * d1;
  ((float2*)A)[i] = r;
}

__global__ __launch_bounds__(128) void scan_kernel(
    const float* __restrict__ A, const float* __restrict__ W_hh,
    const float* __restrict__ fc_w, const float* __restrict__ fc_b,
    float* __restrict__ out) {
  const int b  = threadIdx.x;
  const int c  = blockIdx.x;
  const int t0 = c * CHUNK;
  const int tw = (c == 0) ? 0 : (t0 - WARM);
  const float w2 = SCALE * W_hh[0];
  const float fw = fc_w[0], fb = fc_b[0];
  float h = 0.0f;
  float buf[UNR], nbuf[UNR];
  #pragma unroll
  for (int j = 0; j < UNR; ++j) {
    int t = tw + j; t = (t < T_LEN) ? t : (T_LEN - 1);
    buf[j] = A[t * B_SZ + b];
  }
  const int tlim = t0 + CHUNK;
  for (int tb = tw; tb < tlim; tb += UNR) {
    #pragma unroll
    for (int j = 0; j < UNR; ++j) {
      int t = tb + UNR + j; t = (t < T_LEN) ? t : (T_LEN - 1);
      nbuf[j] = A[t * B_SZ + b];
    }
    #pragma unroll
    for (int j = 0; j < UNR; ++j) {
      const int t = tb + j;
      float g = fmaf(h, w2, buf[j]);
      float u = __builtin_amdgcn_exp2f(g);
      float r = __builtin_amdgcn_rcpf(u + 1.0f);
      h = fmaf(-2.0f, r, 1.0f);
      if (t >= t0 && t < T_LEN) out[t * B_SZ + b] = fmaf(h, fw, fb);
    }
    #pragma unroll
    for (int j = 0; j < UNR; ++j) buf[j] = nbuf[j];
  }
}

// Last-resort fallback (no workspace): fused scan recomputing projection from x.
__global__ __launch_bounds__(128) void scan_fused_kernel(
    const float* __restrict__ x, const float* __restrict__ W_ih,
    const float* __restrict__ W_hh, const float* __restrict__ b_ih,
    const float* __restrict__ b_hh, const float* __restrict__ fc_w,
    const float* __restrict__ fc_b, float* __restrict__ out) {
  const int b  = threadIdx.x;
  const int c  = blockIdx.x;
  const int t0 = c * CHUNK;
  const int tw = (c == 0) ? 0 : (t0 - WARM);
  const float w0 = W_ih[0], w1 = W_ih[1], wv2 = W_ih[2],
              w3 = W_ih[3], w4 = W_ih[4], w5 = W_ih[5];
  const float bias = b_ih[0] + b_hh[0];
  const float w2 = SCALE * W_hh[0];
  const float fw = fc_w[0], fb = fc_b[0];
  float h = 0.0f;
  const int tlim = t0 + CHUNK;
  for (int t = tw; t < tlim; ++t) {
    int tc = (t < T_LEN) ? t : (T_LEN - 1);
    const float2* p = (const float2*)(x + ((size_t)tc * B_SZ + b) * IN_SZ);
    float2 p0 = p[0], p1 = p[1], p2 = p[2];
    float dot = p0.x*w0 + p0.y*w1 + p1.x*wv2 + p1.y*w3 + p2.x*w4 + p2.y*w5 + bias;
    float g = fmaf(h, w2, SCALE * dot);
    float u = __builtin_amdgcn_exp2f(g);
    float r = __builtin_amdgcn_rcpf(u + 1.0f);
    h = fmaf(-2.0f, r, 1.0f);
    if (t >= t0 && t < T_LEN) out[t * B_SZ + b] = fmaf(h, fw, fb);
  }
}

extern "C" void kernel_launch(void* const* d_in, const int* in_sizes, int n_in,
                              void* d_out, int out_size, void* d_ws, size_t ws_size,
                              hipStream_t stream) {
  const float* x    = (const float*)d_in[0];
  const float* W_ih = (const float*)d_in[1];
  const float* W_hh = (const float*)d_in[2];
  const float* b_ih = (const float*)d_in[3];
  const float* b_hh = (const float*)d_in[4];
  const float* fc_w = (const float*)d_in[5];
  const float* fc_b = (const float*)d_in[6];
  float* out = (float*)d_out;

  const size_t needA = (size_t)T_LEN * B_SZ * sizeof(float);

  if (ws_size >= needA) {
    float* A = (float*)d_ws;
    void* args[] = {(void*)&x, (void*)&W_ih, (void*)&W_hh, (void*)&b_ih,
                    (void*)&b_hh, (void*)&fc_w, (void*)&fc_b, (void*)&A,
                    (void*)&out};
    hipError_t e = hipLaunchCooperativeKernel((void*)rnn_fused, dim3(NBLK),
                                              dim3(NTHR), args, 0, stream);
    if (e == hipSuccess) return;
    // cooperative launch unsupported -> proven two-kernel path
    const int n2 = (T_LEN * B_SZ) / 2;
    inproj_kernel<<<(n2 + 255) / 256, 256, 0, stream>>>(x, W_ih, b_ih, b_hh, A, n2);
    scan_kernel<<<NCH, 128, 0, stream>>>(A, W_hh, fc_w, fc_b, out);
  } else {
    scan_fused_kernel<<<NCH, 128, 0, stream>>>(x, W_ih, W_hh, b_ih, b_hh,
                                               fc_w, fc_b, out);
  }
}

// Round 3
// 23.781 us; speedup vs baseline: 4.8616x; 4.8616x over previous
//
#include <hip/hip_runtime.h>
#include <math.h>

// Problem constants (from reference): T=26246, B=128, IN=6, H=1.
#define T_LEN 26246
#define B_SZ  128
// 2*log2(e): tanh(z) = 1 - 2/(2^(SCALE*z) + 1)
#define SCALE 2.88539008177792681472f

#define CHUNK 104   // output steps per block (multiple of UNR)
#define UNR   8     // prefetch group depth (double-buffered)
#define NCH   ((T_LEN + CHUNK - 1) / CHUNK)   // 253 blocks -> ~1 block/CU

// Single fused kernel: per-chunk inline input projection + scalar tanh scan.
// Each block owns output rows [t0, t0+CHUNK); it starts warm steps earlier
// from h=0 — the recurrence is contracting (|dh_t/dh_{t-1}| <= |w|), so the
// truncated-history error is <= |w|^warm, with warm chosen so that's <= 1e-4.
__global__ __launch_bounds__(128) void rnn_scan_fused(
    const float* __restrict__ x, const float* __restrict__ W_ih,
    const float* __restrict__ W_hh, const float* __restrict__ b_ih,
    const float* __restrict__ b_hh, const float* __restrict__ fc_w,
    const float* __restrict__ fc_b, float* __restrict__ out) {
  const int b  = threadIdx.x;           // batch element (lane)
  const int c  = blockIdx.x;            // chunk index
  const int t0 = c * CHUNK;

  const float w  = W_hh[0];
  const float w2 = SCALE * w;
  // Fold SCALE into the projection weights/bias (off the critical chain).
  const float s0 = SCALE * W_ih[0], s1 = SCALE * W_ih[1], s2 = SCALE * W_ih[2],
              s3 = SCALE * W_ih[3], s4 = SCALE * W_ih[4], s5 = SCALE * W_ih[5];
  const float sb = SCALE * (b_ih[0] + b_hh[0]);
  const float fw = fc_w[0], fb = fc_b[0];

  // Adaptive warm-up: |w|^warm <= 1e-4  (warm = ceil(-ln(1e-4)/-ln|w|)).
  int warm = 16;                        // 0.56^16 ~ 9e-5
  {
    float aw = fabsf(w);
    if (aw > 0.56f) {
      float l = logf(fminf(aw, 0.999f));
      warm = (int)ceilf(-9.2103404f / l);
      warm = (warm + UNR - 1) & ~(UNR - 1);
      if (warm > 2048) warm = 2048;
    }
  }
  int tw = t0 - warm;
  if (tw < 0) tw = 0;                   // t0 and warm are multiples of UNR -> tw too
  const int tlim = t0 + CHUNK;          // (tlim - tw) is a multiple of UNR

  float h = 0.0f;
  float2 buf[UNR][3], nbuf[UNR][3];     // statically indexed -> stays in VGPRs

  #pragma unroll
  for (int j = 0; j < UNR; ++j) {
    int t = tw + j; t = (t < T_LEN) ? t : (T_LEN - 1);
    const float2* p = (const float2*)(x + ((size_t)t * B_SZ + b) * 6);
    buf[j][0] = p[0]; buf[j][1] = p[1]; buf[j][2] = p[2];
  }

  for (int tb = tw; tb < tlim; tb += UNR) {
    // Prefetch next group (independent of the h chain; 24 loads in flight).
    #pragma unroll
    for (int j = 0; j < UNR; ++j) {
      int t = tb + UNR + j; t = (t < T_LEN) ? t : (T_LEN - 1);
      const float2* p = (const float2*)(x + ((size_t)t * B_SZ + b) * 6);
      nbuf[j][0] = p[0]; nbuf[j][1] = p[1]; nbuf[j][2] = p[2];
    }
    // UNR dependent recurrence steps (projection is off-chain).
    #pragma unroll
    for (int j = 0; j < UNR; ++j) {
      float a = fmaf(buf[j][0].x, s0, sb);
      a = fmaf(buf[j][0].y, s1, a);
      a = fmaf(buf[j][1].x, s2, a);
      a = fmaf(buf[j][1].y, s3, a);
      a = fmaf(buf[j][2].x, s4, a);
      a = fmaf(buf[j][2].y, s5, a);
      float g = fmaf(h, w2, a);
      float u = __builtin_amdgcn_exp2f(g);
      float r = __builtin_amdgcn_rcpf(u + 1.0f);
      h = fmaf(-2.0f, r, 1.0f);         // tanh(z) = 1 - 2/(2^(2*log2e*z)+1)
      const int t = tb + j;
      if (t >= t0 && t < T_LEN) out[(size_t)t * B_SZ + b] = fmaf(h, fw, fb);
    }
    #pragma unroll
    for (int j = 0; j < UNR; ++j) {
      buf[j][0] = nbuf[j][0]; buf[j][1] = nbuf[j][1]; buf[j][2] = nbuf[j][2];
    }
  }
}

extern "C" void kernel_launch(void* const* d_in, const int* in_sizes, int n_in,
                              void* d_out, int out_size, void* d_ws, size_t ws_size,
                              hipStream_t stream) {
  const float* x    = (const float*)d_in[0];
  const float* W_ih = (const float*)d_in[1];
  const float* W_hh = (const float*)d_in[2];
  const float* b_ih = (const float*)d_in[3];
  const float* b_hh = (const float*)d_in[4];
  const float* fc_w = (const float*)d_in[5];
  const float* fc_b = (const float*)d_in[6];
  float* out = (float*)d_out;

  rnn_scan_fused<<<NCH, 128, 0, stream>>>(x, W_ih, W_hh, b_ih, b_hh,
                                          fc_w, fc_b, out);
}